// Round 14
// baseline (238.926 us; speedup 1.0000x reference)
//
#include <hip/hip_runtime.h>

#define B 8
#define F 257
#define C 8
#define T 800
#define TAPS 5
#define DELAY 3
#define K 40         // TAPS*C
#define NCOL 48      // K + C
#define T0 7         // DELAY + TAPS - 1
#define BF (B*F)     // 2056

typedef __bf16 bf16x8 __attribute__((ext_vector_type(8)));
typedef __bf16 bf16x4 __attribute__((ext_vector_type(4)));
typedef float f32x4 __attribute__((ext_vector_type(4)));

// ---------------- kernel 1: sqrt inverse power weights (0 for t<T0) ----------------
__global__ __launch_bounds__(256) void power_kernel(const float* __restrict__ sr,
                                                    const float* __restrict__ si,
                                                    float* __restrict__ W) {
    int bf = blockIdx.x;
    const float* srp = sr + (size_t)bf * C * T;
    const float* sip = si + (size_t)bf * C * T;
    int t0 = threadIdx.x * 4;
    if (t0 < T) {
        float s[4] = {0.f, 0.f, 0.f, 0.f};
#pragma unroll
        for (int c = 0; c < C; ++c) {
            float4 a = *(const float4*)(srp + c * T + t0);
            float4 b = *(const float4*)(sip + c * T + t0);
            s[0] = fmaf(a.x, a.x, fmaf(b.x, b.x, s[0]));
            s[1] = fmaf(a.y, a.y, fmaf(b.y, b.y, s[1]));
            s[2] = fmaf(a.z, a.z, fmaf(b.z, b.z, s[2]));
            s[3] = fmaf(a.w, a.w, fmaf(b.w, b.w, s[3]));
        }
        float4 w;
        float* wp = (float*)&w;
#pragma unroll
        for (int e = 0; e < 4; ++e) {
            float v = fmaxf(s[e] * (1.0f / C), 1e-7f);
            wp[e] = (t0 + e < T0) ? 0.f : rsqrtf(v);   // sqrt(1/power)
        }
        *(float4*)(W + (size_t)bf * T + t0) = w;
    }
}

// ---------------- kernel 2: R,P via bf16 MFMA, sqrt(w)-symmetrized Gram ----------------
#define WB 10624

__global__ __launch_bounds__(256, 3) void rp_mfma_kernel(const float* __restrict__ mr,
                                                         const float* __restrict__ mi,
                                                         const float* __restrict__ W,
                                                         float2* __restrict__ Rout,
                                                         float2* __restrict__ Pout) {
    __shared__ __align__(16) unsigned char SH[4 * WB];
    const int lane = threadIdx.x & 63;
    const int wid = threadIdx.x >> 6;
    const int bf = blockIdx.x * 4 + wid;
    unsigned char* base = SH + wid * WB;
    float* sre = (float*)(base + 7680);
    float* sim_ = (float*)(base + 9088);
    float* wsh = (float*)(base + 10496);

    const float* mrp = mr + (size_t)bf * C * T;
    const float* mip = mi + (size_t)bf * C * T;
    const float* Wp  = W  + (size_t)bf * T;

    const int q = lane >> 4, col = lane & 15;
    const int pc = lane >> 3, pg = lane & 7;     // phase-B task: channel, 4t-group

    const int PM[6] = {0, 0, 0, 1, 1, 2};
    const int PN[6] = {0, 1, 2, 1, 2, 2};

    f32x4 accRe[6], accIr[6], accRi[6];
#pragma unroll
    for (int p = 0; p < 6; ++p) {
        accRe[p] = (f32x4){0.f, 0.f, 0.f, 0.f};
        accIr[p] = (f32x4){0.f, 0.f, 0.f, 0.f};
        accRi[p] = (f32x4){0.f, 0.f, 0.f, 0.f};
    }

    for (int ks = 0; ks < 25; ++ks) {
        const int tb = ks * 32;

        // ---- Phase A: vectorized global -> fp32 LDS scratch ----
#pragma unroll
        for (int it = 0; it < 3; ++it) {
            int task = lane + it * 64;
            if (task < 160) {
                int pl = task / 80;
                int rem = task - pl * 80;
                int c = rem / 10, grp = rem - c * 10;
                int tg = tb - 8 + grp * 4;
                const float* srcp = pl ? mip : mrp;
                float4 v = make_float4(0.f, 0.f, 0.f, 0.f);
                if (tg >= 0) v = *(const float4*)(srcp + c * T + tg);
                *(float4*)((pl ? sim_ : sre) + c * 44 + grp * 4) = v;
            } else if (task < 168) {
                int grp = task - 160;
                *(float4*)(wsh + grp * 4) = *(const float4*)(Wp + tb + grp * 4);
            }
        }

        // ---- Phase B: build 6 shift-variant bf16 rows from scratch ----
        {
            float yre[12], yim[12];
            int ybase = pc * 44 + pg * 4;
#pragma unroll
            for (int i = 1; i <= 11; ++i) {
                yre[i] = sre[ybase + i];
                yim[i] = sim_[ybase + i];
            }
            float4 w4 = *(const float4*)(wsh + pg * 4);
            float wv[4] = {w4.x, w4.y, w4.z, w4.w};
#pragma unroll
            for (int v = 0; v < 6; ++v) {
                int row = (v < 5) ? (v * 8 + pc) : (40 + pc);
                int off = (v < 5) ? (5 - v) : 8;
                bf16x4 zr, zi;
#pragma unroll
                for (int e = 0; e < 4; ++e) {
                    zr[e] = (__bf16)(wv[e] * yre[off + e]);
                    zi[e] = (__bf16)(wv[e] * yim[off + e]);
                }
                *(bf16x4*)(base + row * 80 + pg * 8) = zr;
                *(bf16x4*)(base + 3840 + row * 80 + pg * 8) = zi;
            }
        }

        // ---- fragments (shared A/B operand) + 24 MFMA ----
        bf16x8 fr[3], fi[3];
#pragma unroll
        for (int X = 0; X < 3; ++X) {
            fr[X] = *(const bf16x8*)(base + (X * 16 + col) * 80 + q * 16);
            fi[X] = *(const bf16x8*)(base + 3840 + (X * 16 + col) * 80 + q * 16);
        }
#pragma unroll
        for (int p = 0; p < 6; ++p) {
            int mt = PM[p], nt = PN[p];
            accRe[p] = __builtin_amdgcn_mfma_f32_16x16x32_bf16(fr[mt], fr[nt], accRe[p], 0, 0, 0);
            accRe[p] = __builtin_amdgcn_mfma_f32_16x16x32_bf16(fi[mt], fi[nt], accRe[p], 0, 0, 0);
            accIr[p] = __builtin_amdgcn_mfma_f32_16x16x32_bf16(fi[mt], fr[nt], accIr[p], 0, 0, 0);
            accRi[p] = __builtin_amdgcn_mfma_f32_16x16x32_bf16(fr[mt], fi[nt], accRi[p], 0, 0, 0);
        }
    }

    // ---- epilogue: D row=(lane>>4)*4+reg, col=lane&15 (m89); Hermitian mirror ----
    // EPS_REG added on the diagonal here.
    float2* Rp = Rout + (size_t)bf * K * K;
    float2* Pp = Pout + (size_t)bf * K * C;
#pragma unroll
    for (int p = 0; p < 6; ++p) {
        int mt = PM[p], nt = PN[p];
#pragma unroll
        for (int r = 0; r < 4; ++r) {
            int m = mt * 16 + q * 4 + r;
            int n = nt * 16 + col;
            float re = accRe[p][r];
            float im = accIr[p][r] - accRi[p][r];
            if (m < K) {
                if (n < K) {
                    if (m == n) re += 1e-10f;
                    Rp[m * K + n] = make_float2(re, im);
                } else {
                    Pp[m * C + (n - K)] = make_float2(re, im);
                }
            }
            if (mt != nt && m < K && n < K)
                Rp[n * K + m] = make_float2(re, -im);
        }
    }
}

// ---------------- kernel 3: solve R G = P — register-row Gauss-Jordan, ZERO LDS ----------------
__device__ __forceinline__ float rdlane(float v, int j) {
    return __uint_as_float(__builtin_amdgcn_readlane(__float_as_uint(v), (unsigned)j));
}

__global__ __launch_bounds__(64) void solve_kernel(const float2* __restrict__ Rin,
                                                   const float2* __restrict__ Pin,
                                                   float2* __restrict__ Gout) {
    const int bf = blockIdx.x;
    const int lane = threadIdx.x;
    const bool act = lane < K;

    float2 row[NCOL];
    {
        const float4* Rp4 = (const float4*)(Rin + (size_t)bf * K * K + (size_t)(act ? lane : 0) * K);
        const float4* Pp4 = (const float4*)(Pin + (size_t)bf * K * C + (size_t)(act ? lane : 0) * C);
#pragma unroll
        for (int m = 0; m < K / 2; ++m) {
            float4 v = Rp4[m];
            if (!act) v = make_float4(0.f, 0.f, 0.f, 0.f);
            row[2 * m]     = make_float2(v.x, v.y);
            row[2 * m + 1] = make_float2(v.z, v.w);
        }
#pragma unroll
        for (int m = 0; m < C / 2; ++m) {
            float4 v = Pp4[m];
            if (!act) v = make_float4(0.f, 0.f, 0.f, 0.f);
            row[K + 2 * m]     = make_float2(v.x, v.y);
            row[K + 2 * m + 1] = make_float2(v.z, v.w);
        }
    }

#pragma unroll
    for (int j = 0; j < K; ++j) {
        float dx = rdlane(row[j].x, j);
        float dy = rdlane(row[j].y, j);
        float den = fmaf(dx, dx, dy * dy);
        float r = 1.0f / den;
        float ix = dx * r;
        float iy = -dy * r;
        float lx = row[j].x * ix - row[j].y * iy;
        float ly = row[j].x * iy + row[j].y * ix;
        bool isj = (lane == j);
        lx = isj ? (1.0f - ix) : lx;
        ly = isj ? (0.0f - iy) : ly;
#pragma unroll
        for (int n = j; n < NCOL; ++n) {
            float ux = rdlane(row[n].x, j);
            float uy = rdlane(row[n].y, j);
            row[n].x = fmaf(-lx, ux, fmaf( ly, uy, row[n].x));
            row[n].y = fmaf(-lx, uy, fmaf(-ly, ux, row[n].y));
        }
    }

    if (act) {
        float4* Gp = (float4*)(Gout + (size_t)bf * K * C + (size_t)lane * C);
#pragma unroll
        for (int m = 0; m < C / 2; ++m)
            Gp[m] = make_float4(row[K + 2 * m].x, row[K + 2 * m].y,
                                row[K + 2 * m + 1].x, row[K + 2 * m + 1].y);
    }
}

// ---------------- kernel 4: X = Y - G^H Yt via bf16 MFMA, G in registers ----------------
// One wave per bf (4 waves/block, wave-private LDS, no barriers).
// A-operand: A[e][a] = G[a][e] (e<8, a<40; else 0) in VGPRs.
// B-operand: Ytilde staged TRANSPOSED in LDS: row t_local, stride 144B, bf16 a index;
//   a in [0,40) real data, bytes [80,128) zero-filled once (fragments read up to 128).
// D[e][t] = sum_a conj(G[a][e])*Yt[a][t]; X = Y - D, masked by ilens.
// Per-wave LDS: Byr @0 (32x144), Byi @4608, sre @9216 (8x44 f32), sim @10624; 12032 B.
#define XSTR 144
#define XWB 12032

__global__ __launch_bounds__(256) void x_mfma_kernel(const float* __restrict__ mr,
                                                     const float* __restrict__ mi,
                                                     const float2* __restrict__ Gin,
                                                     const int* __restrict__ ilens,
                                                     float2* __restrict__ out) {
    __shared__ __align__(16) unsigned char SH[4 * XWB];
    const int lane = threadIdx.x & 63;
    const int wid = threadIdx.x >> 6;
    const int bf = blockIdx.x * 4 + wid;
    unsigned char* base = SH + wid * XWB;
    float* sre = (float*)(base + 9216);
    float* sim_ = (float*)(base + 10624);

    const float* mrp = mr + (size_t)bf * C * T;
    const float* mip = mi + (size_t)bf * C * T;
    const float2* Gp = Gin + (size_t)bf * K * C;
    float2* outp = out + (size_t)bf * C * T;
    const int len = ilens[bf / F];

    const int q = lane >> 4, col = lane & 15;
    const int t2 = lane >> 1, half = lane & 1;   // phase-B task: time row, a-half

    // ---- one-time: zero-fill bytes [80,128) of all rows (a = 40..63 -> 0.0) ----
#pragma unroll
    for (int pl = 0; pl < 2; ++pl) {
        unsigned char* pb = base + pl * 4608 + t2 * XSTR + 80 + half * 24;
        *(float2*)(pb)      = make_float2(0.f, 0.f);
        *(float2*)(pb + 8)  = make_float2(0.f, 0.f);
        *(float2*)(pb + 16) = make_float2(0.f, 0.f);
    }

    // ---- A fragments: G (and -Gi) in registers, built once ----
    bf16x8 Agr[2], Agi[2], Agin[2];
#pragma unroll
    for (int ks = 0; ks < 2; ++ks)
#pragma unroll
        for (int j = 0; j < 8; ++j) {
            int a = ks * 32 + q * 8 + j;
            float2 g = make_float2(0.f, 0.f);
            if (a < K && col < C) g = Gp[a * C + col];
            Agr[ks][j]  = (__bf16)g.x;
            Agi[ks][j]  = (__bf16)g.y;
            Agin[ks][j] = (__bf16)(-g.y);
        }

    for (int ck = 0; ck < 25; ++ck) {
        const int tb = ck * 32;

        // ---- Phase A: vectorized global -> fp32 LDS scratch (t in [tb-8, tb+32)) ----
#pragma unroll
        for (int it = 0; it < 3; ++it) {
            int task = lane + it * 64;
            if (task < 160) {
                int pl = task / 80;
                int rem = task - pl * 80;
                int c = rem / 10, grp = rem - c * 10;
                int tg = tb - 8 + grp * 4;
                const float* srcp = pl ? mip : mrp;
                float4 v = make_float4(0.f, 0.f, 0.f, 0.f);
                if (tg >= 0) v = *(const float4*)(srcp + c * T + tg);
                *(float4*)((pl ? sim_ : sre) + c * 44 + grp * 4) = v;
            }
        }

        // ---- Phase B: build transposed bf16 Ytilde rows [t_local][a] ----
#pragma unroll
        for (int i = 0; i < 5; ++i) {
            int abase = half * 20 + 4 * i;
            bf16x4 zr, zi;
#pragma unroll
            for (int e2 = 0; e2 < 4; ++e2) {
                int a = abase + e2;
                int v = a >> 3, c = a & 7;
                int idx = c * 44 + t2 + 5 - v;   // Y[c][tb+t2-3-v]
                zr[e2] = (__bf16)sre[idx];
                zi[e2] = (__bf16)sim_[idx];
            }
            *(bf16x4*)(base + t2 * XSTR + abase * 2) = zr;
            *(bf16x4*)(base + 4608 + t2 * XSTR + abase * 2) = zi;
        }

        // ---- two 16-t tiles: 8 MFMA each + epilogue ----
#pragma unroll
        for (int tt = 0; tt < 2; ++tt) {
            const int trow = tt * 16 + col;
            f32x4 accRe = (f32x4){0.f, 0.f, 0.f, 0.f};
            f32x4 accIm = (f32x4){0.f, 0.f, 0.f, 0.f};
#pragma unroll
            for (int ks = 0; ks < 2; ++ks) {
                bf16x8 byr = *(const bf16x8*)(base + trow * XSTR + ks * 64 + q * 16);
                bf16x8 byi = *(const bf16x8*)(base + 4608 + trow * XSTR + ks * 64 + q * 16);
                accRe = __builtin_amdgcn_mfma_f32_16x16x32_bf16(Agr[ks], byr, accRe, 0, 0, 0);
                accRe = __builtin_amdgcn_mfma_f32_16x16x32_bf16(Agi[ks], byi, accRe, 0, 0, 0);
                accIm = __builtin_amdgcn_mfma_f32_16x16x32_bf16(Agr[ks], byi, accIm, 0, 0, 0);
                accIm = __builtin_amdgcn_mfma_f32_16x16x32_bf16(Agin[ks], byr, accIm, 0, 0, 0);
            }
            // D row=(lane>>4)*4+r (=e), col=lane&15 (=t offset) [m89]
            if (q < 2) {
                int t = tb + tt * 16 + col;
                bool ok = (t < len);
#pragma unroll
                for (int r = 0; r < 4; ++r) {
                    int e = q * 4 + r;
                    float yr = mrp[e * T + t];
                    float yi = mip[e * T + t];
                    float2 v = ok ? make_float2(yr - accRe[r], yi - accIm[r])
                                  : make_float2(0.f, 0.f);
                    outp[e * T + t] = v;
                }
            }
        }
    }
}

extern "C" void kernel_launch(void* const* d_in, const int* in_sizes, int n_in,
                              void* d_out, int out_size, void* d_ws, size_t ws_size,
                              hipStream_t stream) {
    const float* sep_r = (const float*)d_in[0];
    const float* sep_i = (const float*)d_in[1];
    const float* mix_r = (const float*)d_in[2];
    const float* mix_i = (const float*)d_in[3];
    const int* ilens   = (const int*)d_in[4];

    float* ws = (float*)d_ws;
    float* W = ws;                                        // BF*T floats
    float2* Rws = (float2*)(ws + (size_t)BF * T);         // BF*K*K float2
    float2* Gws = Rws + (size_t)BF * K * K;               // BF*K*C float2 (P then G in-place)

    power_kernel<<<BF, 256, 0, stream>>>(sep_r, sep_i, W);
    rp_mfma_kernel<<<BF / 4, 256, 0, stream>>>(mix_r, mix_i, W, Rws, Gws);
    solve_kernel<<<BF, 64, 0, stream>>>(Rws, Gws, Gws);
    x_mfma_kernel<<<BF / 4, 256, 0, stream>>>(mix_r, mix_i, Gws, ilens, (float2*)d_out);
}

// Round 15
// 225.731 us; speedup vs baseline: 1.0585x; 1.0585x over previous
//
#include <hip/hip_runtime.h>

#define B 8
#define F 257
#define C 8
#define T 800
#define TAPS 5
#define DELAY 3
#define K 40         // TAPS*C
#define NCOL 48      // K + C
#define T0 7         // DELAY + TAPS - 1
#define BF (B*F)     // 2056

typedef __bf16 bf16x8 __attribute__((ext_vector_type(8)));
typedef __bf16 bf16x4 __attribute__((ext_vector_type(4)));
typedef float f32x4 __attribute__((ext_vector_type(4)));

// ---------------- kernel 1: sqrt inverse power weights (0 for t<T0) ----------------
__global__ __launch_bounds__(256) void power_kernel(const float* __restrict__ sr,
                                                    const float* __restrict__ si,
                                                    float* __restrict__ W) {
    int bf = blockIdx.x;
    const float* srp = sr + (size_t)bf * C * T;
    const float* sip = si + (size_t)bf * C * T;
    int t0 = threadIdx.x * 4;
    if (t0 < T) {
        float s[4] = {0.f, 0.f, 0.f, 0.f};
#pragma unroll
        for (int c = 0; c < C; ++c) {
            float4 a = *(const float4*)(srp + c * T + t0);
            float4 b = *(const float4*)(sip + c * T + t0);
            s[0] = fmaf(a.x, a.x, fmaf(b.x, b.x, s[0]));
            s[1] = fmaf(a.y, a.y, fmaf(b.y, b.y, s[1]));
            s[2] = fmaf(a.z, a.z, fmaf(b.z, b.z, s[2]));
            s[3] = fmaf(a.w, a.w, fmaf(b.w, b.w, s[3]));
        }
        float4 w;
        float* wp = (float*)&w;
#pragma unroll
        for (int e = 0; e < 4; ++e) {
            float v = fmaxf(s[e] * (1.0f / C), 1e-7f);
            wp[e] = (t0 + e < T0) ? 0.f : rsqrtf(v);   // sqrt(1/power)
        }
        *(float4*)(W + (size_t)bf * T + t0) = w;
    }
}

// ---------------- kernel 2: R,P via bf16 MFMA — ONE WAVE PER BLOCK ----------------
#define WB 10624

__global__ __launch_bounds__(64) void rp_mfma_kernel(const float* __restrict__ mr,
                                                     const float* __restrict__ mi,
                                                     const float* __restrict__ W,
                                                     float2* __restrict__ Rout,
                                                     float2* __restrict__ Pout) {
    __shared__ __align__(16) unsigned char SH[WB];
    const int lane = threadIdx.x;
    const int bf = blockIdx.x;
    unsigned char* base = SH;
    float* sre = (float*)(base + 7680);
    float* sim_ = (float*)(base + 9088);
    float* wsh = (float*)(base + 10496);

    const float* mrp = mr + (size_t)bf * C * T;
    const float* mip = mi + (size_t)bf * C * T;
    const float* Wp  = W  + (size_t)bf * T;

    const int q = lane >> 4, col = lane & 15;
    const int pc = lane >> 3, pg = lane & 7;     // phase-B task: channel, 4t-group

    const int PM[6] = {0, 0, 0, 1, 1, 2};
    const int PN[6] = {0, 1, 2, 1, 2, 2};

    f32x4 accRe[6], accIr[6], accRi[6];
#pragma unroll
    for (int p = 0; p < 6; ++p) {
        accRe[p] = (f32x4){0.f, 0.f, 0.f, 0.f};
        accIr[p] = (f32x4){0.f, 0.f, 0.f, 0.f};
        accRi[p] = (f32x4){0.f, 0.f, 0.f, 0.f};
    }

    for (int ks = 0; ks < 25; ++ks) {
        const int tb = ks * 32;

        // ---- Phase A: vectorized global -> fp32 LDS scratch ----
#pragma unroll
        for (int it = 0; it < 3; ++it) {
            int task = lane + it * 64;
            if (task < 160) {
                int pl = task / 80;
                int rem = task - pl * 80;
                int c = rem / 10, grp = rem - c * 10;
                int tg = tb - 8 + grp * 4;
                const float* srcp = pl ? mip : mrp;
                float4 v = make_float4(0.f, 0.f, 0.f, 0.f);
                if (tg >= 0) v = *(const float4*)(srcp + c * T + tg);
                *(float4*)((pl ? sim_ : sre) + c * 44 + grp * 4) = v;
            } else if (task < 168) {
                int grp = task - 160;
                *(float4*)(wsh + grp * 4) = *(const float4*)(Wp + tb + grp * 4);
            }
        }

        // ---- Phase B: build 6 shift-variant bf16 rows from scratch ----
        {
            float yre[12], yim[12];
            int ybase = pc * 44 + pg * 4;
#pragma unroll
            for (int i = 1; i <= 11; ++i) {
                yre[i] = sre[ybase + i];
                yim[i] = sim_[ybase + i];
            }
            float4 w4 = *(const float4*)(wsh + pg * 4);
            float wv[4] = {w4.x, w4.y, w4.z, w4.w};
#pragma unroll
            for (int v = 0; v < 6; ++v) {
                int row = (v < 5) ? (v * 8 + pc) : (40 + pc);
                int off = (v < 5) ? (5 - v) : 8;
                bf16x4 zr, zi;
#pragma unroll
                for (int e = 0; e < 4; ++e) {
                    zr[e] = (__bf16)(wv[e] * yre[off + e]);
                    zi[e] = (__bf16)(wv[e] * yim[off + e]);
                }
                *(bf16x4*)(base + row * 80 + pg * 8) = zr;
                *(bf16x4*)(base + 3840 + row * 80 + pg * 8) = zi;
            }
        }

        // ---- fragments (shared A/B operand) + 24 MFMA ----
        bf16x8 fr[3], fi[3];
#pragma unroll
        for (int X = 0; X < 3; ++X) {
            fr[X] = *(const bf16x8*)(base + (X * 16 + col) * 80 + q * 16);
            fi[X] = *(const bf16x8*)(base + 3840 + (X * 16 + col) * 80 + q * 16);
        }
#pragma unroll
        for (int p = 0; p < 6; ++p) {
            int mt = PM[p], nt = PN[p];
            accRe[p] = __builtin_amdgcn_mfma_f32_16x16x32_bf16(fr[mt], fr[nt], accRe[p], 0, 0, 0);
            accRe[p] = __builtin_amdgcn_mfma_f32_16x16x32_bf16(fi[mt], fi[nt], accRe[p], 0, 0, 0);
            accIr[p] = __builtin_amdgcn_mfma_f32_16x16x32_bf16(fi[mt], fr[nt], accIr[p], 0, 0, 0);
            accRi[p] = __builtin_amdgcn_mfma_f32_16x16x32_bf16(fr[mt], fi[nt], accRi[p], 0, 0, 0);
        }
    }

    // ---- epilogue: D row=(lane>>4)*4+reg, col=lane&15 (m89); Hermitian mirror ----
    // EPS_REG added on the diagonal here.
    float2* Rp = Rout + (size_t)bf * K * K;
    float2* Pp = Pout + (size_t)bf * K * C;
#pragma unroll
    for (int p = 0; p < 6; ++p) {
        int mt = PM[p], nt = PN[p];
#pragma unroll
        for (int r = 0; r < 4; ++r) {
            int m = mt * 16 + q * 4 + r;
            int n = nt * 16 + col;
            float re = accRe[p][r];
            float im = accIr[p][r] - accRi[p][r];
            if (m < K) {
                if (n < K) {
                    if (m == n) re += 1e-10f;
                    Rp[m * K + n] = make_float2(re, im);
                } else {
                    Pp[m * C + (n - K)] = make_float2(re, im);
                }
            }
            if (mt != nt && m < K && n < K)
                Rp[n * K + m] = make_float2(re, -im);
        }
    }
}

// ---------------- kernel 3: solve R G = P — register-row Gauss-Jordan, ZERO LDS ----------------
__device__ __forceinline__ float rdlane(float v, int j) {
    return __uint_as_float(__builtin_amdgcn_readlane(__float_as_uint(v), (unsigned)j));
}

__global__ __launch_bounds__(64) void solve_kernel(const float2* __restrict__ Rin,
                                                   const float2* __restrict__ Pin,
                                                   float2* __restrict__ Gout) {
    const int bf = blockIdx.x;
    const int lane = threadIdx.x;
    const bool act = lane < K;

    float2 row[NCOL];
    {
        const float4* Rp4 = (const float4*)(Rin + (size_t)bf * K * K + (size_t)(act ? lane : 0) * K);
        const float4* Pp4 = (const float4*)(Pin + (size_t)bf * K * C + (size_t)(act ? lane : 0) * C);
#pragma unroll
        for (int m = 0; m < K / 2; ++m) {
            float4 v = Rp4[m];
            if (!act) v = make_float4(0.f, 0.f, 0.f, 0.f);
            row[2 * m]     = make_float2(v.x, v.y);
            row[2 * m + 1] = make_float2(v.z, v.w);
        }
#pragma unroll
        for (int m = 0; m < C / 2; ++m) {
            float4 v = Pp4[m];
            if (!act) v = make_float4(0.f, 0.f, 0.f, 0.f);
            row[K + 2 * m]     = make_float2(v.x, v.y);
            row[K + 2 * m + 1] = make_float2(v.z, v.w);
        }
    }

#pragma unroll
    for (int j = 0; j < K; ++j) {
        float dx = rdlane(row[j].x, j);
        float dy = rdlane(row[j].y, j);
        float den = fmaf(dx, dx, dy * dy);
        float r = 1.0f / den;
        float ix = dx * r;
        float iy = -dy * r;
        float lx = row[j].x * ix - row[j].y * iy;
        float ly = row[j].x * iy + row[j].y * ix;
        bool isj = (lane == j);
        lx = isj ? (1.0f - ix) : lx;
        ly = isj ? (0.0f - iy) : ly;
#pragma unroll
        for (int n = j; n < NCOL; ++n) {
            float ux = rdlane(row[n].x, j);
            float uy = rdlane(row[n].y, j);
            row[n].x = fmaf(-lx, ux, fmaf( ly, uy, row[n].x));
            row[n].y = fmaf(-lx, uy, fmaf(-ly, ux, row[n].y));
        }
    }

    if (act) {
        float4* Gp = (float4*)(Gout + (size_t)bf * K * C + (size_t)lane * C);
#pragma unroll
        for (int m = 0; m < C / 2; ++m)
            Gp[m] = make_float4(row[K + 2 * m].x, row[K + 2 * m].y,
                                row[K + 2 * m + 1].x, row[K + 2 * m + 1].y);
    }
}

// ---------------- kernel 4: X = Y - G^H Yt via bf16 MFMA — ONE WAVE PER BLOCK, 4-way t-split ----------------
// Block = 1 wave, handles a contiguous range of 32-t chunks of one bf.
// A-operand: A[e][a] = G[a][e] (e<8, a<40; else 0) in VGPRs.
// B-operand: Ytilde staged TRANSPOSED in LDS: row t_local, stride 144B, bf16 a index;
//   a in [0,40) real data, bytes [80,128) zero-filled once.
// Per-block LDS: Byr @0 (32x144), Byi @4608, sre @9216 (8x44 f32), sim @10624; 12032 B.
#define XSTR 144
#define XWB 12032

__global__ __launch_bounds__(64) void x_mfma_kernel(const float* __restrict__ mr,
                                                    const float* __restrict__ mi,
                                                    const float2* __restrict__ Gin,
                                                    const int* __restrict__ ilens,
                                                    float2* __restrict__ out) {
    __shared__ __align__(16) unsigned char SH[XWB];
    const int lane = threadIdx.x;
    const int gid = blockIdx.x;
    const int bf = gid >> 2;
    const int split = gid & 3;
    // chunk ranges: {0-6}, {7-12}, {13-18}, {19-24}
    const int ck0 = (split == 0) ? 0 : (1 + split * 6);
    const int nck = (split == 0) ? 7 : 6;
    unsigned char* base = SH;
    float* sre = (float*)(base + 9216);
    float* sim_ = (float*)(base + 10624);

    const float* mrp = mr + (size_t)bf * C * T;
    const float* mip = mi + (size_t)bf * C * T;
    const float2* Gp = Gin + (size_t)bf * K * C;
    float2* outp = out + (size_t)bf * C * T;
    const int len = ilens[bf / F];

    const int q = lane >> 4, col = lane & 15;
    const int t2 = lane >> 1, half = lane & 1;   // phase-B task: time row, a-half

    // ---- one-time: zero-fill bytes [80,128) of all rows (a = 40..63 -> 0.0) ----
#pragma unroll
    for (int pl = 0; pl < 2; ++pl) {
        unsigned char* pb = base + pl * 4608 + t2 * XSTR + 80 + half * 24;
        *(float2*)(pb)      = make_float2(0.f, 0.f);
        *(float2*)(pb + 8)  = make_float2(0.f, 0.f);
        *(float2*)(pb + 16) = make_float2(0.f, 0.f);
    }

    // ---- A fragments: G (and -Gi) in registers, built once ----
    bf16x8 Agr[2], Agi[2], Agin[2];
#pragma unroll
    for (int ks = 0; ks < 2; ++ks)
#pragma unroll
        for (int j = 0; j < 8; ++j) {
            int a = ks * 32 + q * 8 + j;
            float2 g = make_float2(0.f, 0.f);
            if (a < K && col < C) g = Gp[a * C + col];
            Agr[ks][j]  = (__bf16)g.x;
            Agi[ks][j]  = (__bf16)g.y;
            Agin[ks][j] = (__bf16)(-g.y);
        }

    for (int ci = 0; ci < nck; ++ci) {
        const int tb = (ck0 + ci) * 32;

        // ---- Phase A: vectorized global -> fp32 LDS scratch (t in [tb-8, tb+32)) ----
#pragma unroll
        for (int it = 0; it < 3; ++it) {
            int task = lane + it * 64;
            if (task < 160) {
                int pl = task / 80;
                int rem = task - pl * 80;
                int c = rem / 10, grp = rem - c * 10;
                int tg = tb - 8 + grp * 4;
                const float* srcp = pl ? mip : mrp;
                float4 v = make_float4(0.f, 0.f, 0.f, 0.f);
                if (tg >= 0) v = *(const float4*)(srcp + c * T + tg);
                *(float4*)((pl ? sim_ : sre) + c * 44 + grp * 4) = v;
            }
        }

        // ---- Phase B: build transposed bf16 Ytilde rows [t_local][a] ----
#pragma unroll
        for (int i = 0; i < 5; ++i) {
            int abase = half * 20 + 4 * i;
            bf16x4 zr, zi;
#pragma unroll
            for (int e2 = 0; e2 < 4; ++e2) {
                int a = abase + e2;
                int v = a >> 3, c = a & 7;
                int idx = c * 44 + t2 + 5 - v;   // Y[c][tb+t2-3-v]
                zr[e2] = (__bf16)sre[idx];
                zi[e2] = (__bf16)sim_[idx];
            }
            *(bf16x4*)(base + t2 * XSTR + abase * 2) = zr;
            *(bf16x4*)(base + 4608 + t2 * XSTR + abase * 2) = zi;
        }

        // ---- two 16-t tiles: 8 MFMA each + epilogue ----
#pragma unroll
        for (int tt = 0; tt < 2; ++tt) {
            const int trow = tt * 16 + col;
            f32x4 accRe = (f32x4){0.f, 0.f, 0.f, 0.f};
            f32x4 accIm = (f32x4){0.f, 0.f, 0.f, 0.f};
#pragma unroll
            for (int ks = 0; ks < 2; ++ks) {
                bf16x8 byr = *(const bf16x8*)(base + trow * XSTR + ks * 64 + q * 16);
                bf16x8 byi = *(const bf16x8*)(base + 4608 + trow * XSTR + ks * 64 + q * 16);
                accRe = __builtin_amdgcn_mfma_f32_16x16x32_bf16(Agr[ks], byr, accRe, 0, 0, 0);
                accRe = __builtin_amdgcn_mfma_f32_16x16x32_bf16(Agi[ks], byi, accRe, 0, 0, 0);
                accIm = __builtin_amdgcn_mfma_f32_16x16x32_bf16(Agr[ks], byi, accIm, 0, 0, 0);
                accIm = __builtin_amdgcn_mfma_f32_16x16x32_bf16(Agin[ks], byr, accIm, 0, 0, 0);
            }
            // D row=(lane>>4)*4+r (=e), col=lane&15 (=t offset) [m89]
            if (q < 2) {
                int t = tb + tt * 16 + col;
                bool ok = (t < len);
#pragma unroll
                for (int r = 0; r < 4; ++r) {
                    int e = q * 4 + r;
                    float yr = mrp[e * T + t];
                    float yi = mip[e * T + t];
                    float2 v = ok ? make_float2(yr - accRe[r], yi - accIm[r])
                                  : make_float2(0.f, 0.f);
                    outp[e * T + t] = v;
                }
            }
        }
    }
}

extern "C" void kernel_launch(void* const* d_in, const int* in_sizes, int n_in,
                              void* d_out, int out_size, void* d_ws, size_t ws_size,
                              hipStream_t stream) {
    const float* sep_r = (const float*)d_in[0];
    const float* sep_i = (const float*)d_in[1];
    const float* mix_r = (const float*)d_in[2];
    const float* mix_i = (const float*)d_in[3];
    const int* ilens   = (const int*)d_in[4];

    float* ws = (float*)d_ws;
    float* W = ws;                                        // BF*T floats
    float2* Rws = (float2*)(ws + (size_t)BF * T);         // BF*K*K float2
    float2* Gws = Rws + (size_t)BF * K * K;               // BF*K*C float2 (P then G in-place)

    power_kernel<<<BF, 256, 0, stream>>>(sep_r, sep_i, W);
    rp_mfma_kernel<<<BF, 64, 0, stream>>>(mix_r, mix_i, W, Rws, Gws);
    solve_kernel<<<BF, 64, 0, stream>>>(Rws, Gws, Gws);
    x_mfma_kernel<<<BF * 4, 64, 0, stream>>>(mix_r, mix_i, Gws, ilens, (float2*)d_out);
}

// Round 16
// 211.095 us; speedup vs baseline: 1.1318x; 1.0693x over previous
//
#include <hip/hip_runtime.h>

#define B 8
#define F 257
#define C 8
#define T 800
#define TAPS 5
#define DELAY 3
#define K 40         // TAPS*C
#define NCOL 48      // K + C
#define T0 7         // DELAY + TAPS - 1
#define BF (B*F)     // 2056

typedef __bf16 bf16x8 __attribute__((ext_vector_type(8)));
typedef __bf16 bf16x4 __attribute__((ext_vector_type(4)));
typedef float f32x4 __attribute__((ext_vector_type(4)));

struct PF { float4 v[3]; };

// ---------------- kernel 1: sqrt inverse power weights (0 for t<T0) ----------------
__global__ __launch_bounds__(256) void power_kernel(const float* __restrict__ sr,
                                                    const float* __restrict__ si,
                                                    float* __restrict__ W) {
    int bf = blockIdx.x;
    const float* srp = sr + (size_t)bf * C * T;
    const float* sip = si + (size_t)bf * C * T;
    int t0 = threadIdx.x * 4;
    if (t0 < T) {
        float s[4] = {0.f, 0.f, 0.f, 0.f};
#pragma unroll
        for (int c = 0; c < C; ++c) {
            float4 a = *(const float4*)(srp + c * T + t0);
            float4 b = *(const float4*)(sip + c * T + t0);
            s[0] = fmaf(a.x, a.x, fmaf(b.x, b.x, s[0]));
            s[1] = fmaf(a.y, a.y, fmaf(b.y, b.y, s[1]));
            s[2] = fmaf(a.z, a.z, fmaf(b.z, b.z, s[2]));
            s[3] = fmaf(a.w, a.w, fmaf(b.w, b.w, s[3]));
        }
        float4 w;
        float* wp = (float*)&w;
#pragma unroll
        for (int e = 0; e < 4; ++e) {
            float v = fmaxf(s[e] * (1.0f / C), 1e-7f);
            wp[e] = (t0 + e < T0) ? 0.f : rsqrtf(v);   // sqrt(1/power)
        }
        *(float4*)(W + (size_t)bf * T + t0) = w;
    }
}

// ---------------- kernel 2: R,P via bf16 MFMA — 1 wave/block + prefetch ----------------
#define WB 10624

__device__ __forceinline__ PF rp_load(const float* __restrict__ mrp,
                                      const float* __restrict__ mip,
                                      const float* __restrict__ Wp,
                                      int tb, int lane) {
    PF p;
#pragma unroll
    for (int it = 0; it < 3; ++it) {
        int task = lane + it * 64;
        float4 v = make_float4(0.f, 0.f, 0.f, 0.f);
        if (task < 160) {
            int pl = task / 80;
            int rem = task - pl * 80;
            int c = rem / 10, grp = rem - c * 10;
            int tg = tb - 8 + grp * 4;
            const float* srcp = pl ? mip : mrp;
            if (tg >= 0) v = *(const float4*)(srcp + c * T + tg);
        } else if (task < 168) {
            int grp = task - 160;
            v = *(const float4*)(Wp + tb + grp * 4);
        }
        p.v[it] = v;
    }
    return p;
}

__device__ __forceinline__ void rp_store(const PF& p, float* sre, float* sim_,
                                         float* wsh, int lane) {
#pragma unroll
    for (int it = 0; it < 3; ++it) {
        int task = lane + it * 64;
        if (task < 160) {
            int pl = task / 80;
            int rem = task - pl * 80;
            int c = rem / 10, grp = rem - c * 10;
            *(float4*)((pl ? sim_ : sre) + c * 44 + grp * 4) = p.v[it];
        } else if (task < 168) {
            int grp = task - 160;
            *(float4*)(wsh + grp * 4) = p.v[it];
        }
    }
}

__global__ __launch_bounds__(64) void rp_mfma_kernel(const float* __restrict__ mr,
                                                     const float* __restrict__ mi,
                                                     const float* __restrict__ W,
                                                     float2* __restrict__ Rout,
                                                     float2* __restrict__ Pout) {
    __shared__ __align__(16) unsigned char SH[WB];
    const int lane = threadIdx.x;
    const int bf = blockIdx.x;
    unsigned char* base = SH;
    float* sre = (float*)(base + 7680);
    float* sim_ = (float*)(base + 9088);
    float* wsh = (float*)(base + 10496);

    const float* mrp = mr + (size_t)bf * C * T;
    const float* mip = mi + (size_t)bf * C * T;
    const float* Wp  = W  + (size_t)bf * T;

    const int q = lane >> 4, col = lane & 15;
    const int pc = lane >> 3, pg = lane & 7;

    const int PM[6] = {0, 0, 0, 1, 1, 2};
    const int PN[6] = {0, 1, 2, 1, 2, 2};

    f32x4 accRe[6], accIr[6], accRi[6];
#pragma unroll
    for (int p = 0; p < 6; ++p) {
        accRe[p] = (f32x4){0.f, 0.f, 0.f, 0.f};
        accIr[p] = (f32x4){0.f, 0.f, 0.f, 0.f};
        accRi[p] = (f32x4){0.f, 0.f, 0.f, 0.f};
    }

    PF cur = rp_load(mrp, mip, Wp, 0, lane);

    for (int ks = 0; ks < 25; ++ks) {
        // ---- write staged chunk to scratch ----
        rp_store(cur, sre, sim_, wsh, lane);
        // ---- prefetch next chunk (in flight across Phase B + MFMA) ----
        if (ks < 24) cur = rp_load(mrp, mip, Wp, (ks + 1) * 32, lane);

        // ---- Phase B: build 6 shift-variant bf16 rows from scratch ----
        {
            float yre[12], yim[12];
            int ybase = pc * 44 + pg * 4;
#pragma unroll
            for (int i = 1; i <= 11; ++i) {
                yre[i] = sre[ybase + i];
                yim[i] = sim_[ybase + i];
            }
            float4 w4 = *(const float4*)(wsh + pg * 4);
            float wv[4] = {w4.x, w4.y, w4.z, w4.w};
#pragma unroll
            for (int v = 0; v < 6; ++v) {
                int row = (v < 5) ? (v * 8 + pc) : (40 + pc);
                int off = (v < 5) ? (5 - v) : 8;
                bf16x4 zr, zi;
#pragma unroll
                for (int e = 0; e < 4; ++e) {
                    zr[e] = (__bf16)(wv[e] * yre[off + e]);
                    zi[e] = (__bf16)(wv[e] * yim[off + e]);
                }
                *(bf16x4*)(base + row * 80 + pg * 8) = zr;
                *(bf16x4*)(base + 3840 + row * 80 + pg * 8) = zi;
            }
        }

        // ---- fragments (shared A/B operand) + 24 MFMA ----
        bf16x8 fr[3], fi[3];
#pragma unroll
        for (int X = 0; X < 3; ++X) {
            fr[X] = *(const bf16x8*)(base + (X * 16 + col) * 80 + q * 16);
            fi[X] = *(const bf16x8*)(base + 3840 + (X * 16 + col) * 80 + q * 16);
        }
#pragma unroll
        for (int p = 0; p < 6; ++p) {
            int mt = PM[p], nt = PN[p];
            accRe[p] = __builtin_amdgcn_mfma_f32_16x16x32_bf16(fr[mt], fr[nt], accRe[p], 0, 0, 0);
            accRe[p] = __builtin_amdgcn_mfma_f32_16x16x32_bf16(fi[mt], fi[nt], accRe[p], 0, 0, 0);
            accIr[p] = __builtin_amdgcn_mfma_f32_16x16x32_bf16(fi[mt], fr[nt], accIr[p], 0, 0, 0);
            accRi[p] = __builtin_amdgcn_mfma_f32_16x16x32_bf16(fr[mt], fi[nt], accRi[p], 0, 0, 0);
        }
    }

    // ---- epilogue: D row=(lane>>4)*4+reg, col=lane&15 (m89); Hermitian mirror ----
    float2* Rp = Rout + (size_t)bf * K * K;
    float2* Pp = Pout + (size_t)bf * K * C;
#pragma unroll
    for (int p = 0; p < 6; ++p) {
        int mt = PM[p], nt = PN[p];
#pragma unroll
        for (int r = 0; r < 4; ++r) {
            int m = mt * 16 + q * 4 + r;
            int n = nt * 16 + col;
            float re = accRe[p][r];
            float im = accIr[p][r] - accRi[p][r];
            if (m < K) {
                if (n < K) {
                    if (m == n) re += 1e-10f;
                    Rp[m * K + n] = make_float2(re, im);
                } else {
                    Pp[m * C + (n - K)] = make_float2(re, im);
                }
            }
            if (mt != nt && m < K && n < K)
                Rp[n * K + m] = make_float2(re, -im);
        }
    }
}

// ---------------- kernel 3: solve R G = P — register-row Gauss-Jordan, ZERO LDS ----------------
__device__ __forceinline__ float rdlane(float v, int j) {
    return __uint_as_float(__builtin_amdgcn_readlane(__float_as_uint(v), (unsigned)j));
}

__global__ __launch_bounds__(64) void solve_kernel(const float2* __restrict__ Rin,
                                                   const float2* __restrict__ Pin,
                                                   float2* __restrict__ Gout) {
    const int bf = blockIdx.x;
    const int lane = threadIdx.x;
    const bool act = lane < K;

    float2 row[NCOL];
    {
        const float4* Rp4 = (const float4*)(Rin + (size_t)bf * K * K + (size_t)(act ? lane : 0) * K);
        const float4* Pp4 = (const float4*)(Pin + (size_t)bf * K * C + (size_t)(act ? lane : 0) * C);
#pragma unroll
        for (int m = 0; m < K / 2; ++m) {
            float4 v = Rp4[m];
            if (!act) v = make_float4(0.f, 0.f, 0.f, 0.f);
            row[2 * m]     = make_float2(v.x, v.y);
            row[2 * m + 1] = make_float2(v.z, v.w);
        }
#pragma unroll
        for (int m = 0; m < C / 2; ++m) {
            float4 v = Pp4[m];
            if (!act) v = make_float4(0.f, 0.f, 0.f, 0.f);
            row[K + 2 * m]     = make_float2(v.x, v.y);
            row[K + 2 * m + 1] = make_float2(v.z, v.w);
        }
    }

#pragma unroll
    for (int j = 0; j < K; ++j) {
        float dx = rdlane(row[j].x, j);
        float dy = rdlane(row[j].y, j);
        float den = fmaf(dx, dx, dy * dy);
        float r = 1.0f / den;
        float ix = dx * r;
        float iy = -dy * r;
        float lx = row[j].x * ix - row[j].y * iy;
        float ly = row[j].x * iy + row[j].y * ix;
        bool isj = (lane == j);
        lx = isj ? (1.0f - ix) : lx;
        ly = isj ? (0.0f - iy) : ly;
#pragma unroll
        for (int n = j; n < NCOL; ++n) {
            float ux = rdlane(row[n].x, j);
            float uy = rdlane(row[n].y, j);
            row[n].x = fmaf(-lx, ux, fmaf( ly, uy, row[n].x));
            row[n].y = fmaf(-lx, uy, fmaf(-ly, ux, row[n].y));
        }
    }

    if (act) {
        float4* Gp = (float4*)(Gout + (size_t)bf * K * C + (size_t)lane * C);
#pragma unroll
        for (int m = 0; m < C / 2; ++m)
            Gp[m] = make_float4(row[K + 2 * m].x, row[K + 2 * m].y,
                                row[K + 2 * m + 1].x, row[K + 2 * m + 1].y);
    }
}

// ---------------- kernel 4: X via bf16 MFMA — prefetch + epilogue-Y-from-LDS ----------------
#define XSTR 144
#define XWB 12032

__device__ __forceinline__ PF x_load(const float* __restrict__ mrp,
                                     const float* __restrict__ mip,
                                     int tb, int lane) {
    PF p;
#pragma unroll
    for (int it = 0; it < 3; ++it) {
        int task = lane + it * 64;
        float4 v = make_float4(0.f, 0.f, 0.f, 0.f);
        if (task < 160) {
            int pl = task / 80;
            int rem = task - pl * 80;
            int c = rem / 10, grp = rem - c * 10;
            int tg = tb - 8 + grp * 4;
            const float* srcp = pl ? mip : mrp;
            if (tg >= 0) v = *(const float4*)(srcp + c * T + tg);
        }
        p.v[it] = v;
    }
    return p;
}

__device__ __forceinline__ void x_store(const PF& p, float* sre, float* sim_, int lane) {
#pragma unroll
    for (int it = 0; it < 3; ++it) {
        int task = lane + it * 64;
        if (task < 160) {
            int pl = task / 80;
            int rem = task - pl * 80;
            int c = rem / 10, grp = rem - c * 10;
            *(float4*)((pl ? sim_ : sre) + c * 44 + grp * 4) = p.v[it];
        }
    }
}

__global__ __launch_bounds__(64) void x_mfma_kernel(const float* __restrict__ mr,
                                                    const float* __restrict__ mi,
                                                    const float2* __restrict__ Gin,
                                                    const int* __restrict__ ilens,
                                                    float2* __restrict__ out) {
    __shared__ __align__(16) unsigned char SH[XWB];
    const int lane = threadIdx.x;
    const int gid = blockIdx.x;
    const int bf = gid >> 2;
    const int split = gid & 3;
    const int ck0 = (split == 0) ? 0 : (1 + split * 6);
    const int nck = (split == 0) ? 7 : 6;
    unsigned char* base = SH;
    float* sre = (float*)(base + 9216);
    float* sim_ = (float*)(base + 10624);

    const float* mrp = mr + (size_t)bf * C * T;
    const float* mip = mi + (size_t)bf * C * T;
    const float2* Gp = Gin + (size_t)bf * K * C;
    float2* outp = out + (size_t)bf * C * T;
    const int len = ilens[bf / F];

    const int q = lane >> 4, col = lane & 15;
    const int t2 = lane >> 1, half = lane & 1;

    // ---- one-time: zero-fill bytes [80,128) of all rows (a = 40..63 -> 0.0) ----
#pragma unroll
    for (int pl = 0; pl < 2; ++pl) {
        unsigned char* pb = base + pl * 4608 + t2 * XSTR + 80 + half * 24;
        *(float2*)(pb)      = make_float2(0.f, 0.f);
        *(float2*)(pb + 8)  = make_float2(0.f, 0.f);
        *(float2*)(pb + 16) = make_float2(0.f, 0.f);
    }

    // ---- A fragments: G (and -Gi) in registers, built once ----
    bf16x8 Agr[2], Agi[2], Agin[2];
#pragma unroll
    for (int ks = 0; ks < 2; ++ks)
#pragma unroll
        for (int j = 0; j < 8; ++j) {
            int a = ks * 32 + q * 8 + j;
            float2 g = make_float2(0.f, 0.f);
            if (a < K && col < C) g = Gp[a * C + col];
            Agr[ks][j]  = (__bf16)g.x;
            Agi[ks][j]  = (__bf16)g.y;
            Agin[ks][j] = (__bf16)(-g.y);
        }

    PF cur = x_load(mrp, mip, ck0 * 32, lane);

    for (int ci = 0; ci < nck; ++ci) {
        const int tb = (ck0 + ci) * 32;

        // ---- write staged chunk; prefetch next ----
        x_store(cur, sre, sim_, lane);
        if (ci + 1 < nck) cur = x_load(mrp, mip, tb + 32, lane);

        // ---- Phase B: build transposed bf16 Ytilde rows [t_local][a] ----
#pragma unroll
        for (int i = 0; i < 5; ++i) {
            int abase = half * 20 + 4 * i;
            bf16x4 zr, zi;
#pragma unroll
            for (int e2 = 0; e2 < 4; ++e2) {
                int a = abase + e2;
                int v = a >> 3, c = a & 7;
                int idx = c * 44 + t2 + 5 - v;   // Y[c][tb+t2-3-v]
                zr[e2] = (__bf16)sre[idx];
                zi[e2] = (__bf16)sim_[idx];
            }
            *(bf16x4*)(base + t2 * XSTR + abase * 2) = zr;
            *(bf16x4*)(base + 4608 + t2 * XSTR + abase * 2) = zi;
        }

        // ---- two 16-t tiles: 8 MFMA each + epilogue (Y from scratch LDS) ----
#pragma unroll
        for (int tt = 0; tt < 2; ++tt) {
            const int trow = tt * 16 + col;
            f32x4 accRe = (f32x4){0.f, 0.f, 0.f, 0.f};
            f32x4 accIm = (f32x4){0.f, 0.f, 0.f, 0.f};
#pragma unroll
            for (int ks = 0; ks < 2; ++ks) {
                bf16x8 byr = *(const bf16x8*)(base + trow * XSTR + ks * 64 + q * 16);
                bf16x8 byi = *(const bf16x8*)(base + 4608 + trow * XSTR + ks * 64 + q * 16);
                accRe = __builtin_amdgcn_mfma_f32_16x16x32_bf16(Agr[ks], byr, accRe, 0, 0, 0);
                accRe = __builtin_amdgcn_mfma_f32_16x16x32_bf16(Agi[ks], byi, accRe, 0, 0, 0);
                accIm = __builtin_amdgcn_mfma_f32_16x16x32_bf16(Agr[ks], byi, accIm, 0, 0, 0);
                accIm = __builtin_amdgcn_mfma_f32_16x16x32_bf16(Agin[ks], byr, accIm, 0, 0, 0);
            }
            // D row=(lane>>4)*4+r (=e), col=lane&15 (=t offset) [m89]
            if (q < 2) {
                int t = tb + tt * 16 + col;
                int l = tt * 16 + col + 8;       // scratch index of t
                bool ok = (t < len);
#pragma unroll
                for (int r = 0; r < 4; ++r) {
                    int e = q * 4 + r;
                    float yr = sre[e * 44 + l];
                    float yi = sim_[e * 44 + l];
                    float2 v = ok ? make_float2(yr - accRe[r], yi - accIm[r])
                                  : make_float2(0.f, 0.f);
                    outp[e * T + t] = v;
                }
            }
        }
    }
}

extern "C" void kernel_launch(void* const* d_in, const int* in_sizes, int n_in,
                              void* d_out, int out_size, void* d_ws, size_t ws_size,
                              hipStream_t stream) {
    const float* sep_r = (const float*)d_in[0];
    const float* sep_i = (const float*)d_in[1];
    const float* mix_r = (const float*)d_in[2];
    const float* mix_i = (const float*)d_in[3];
    const int* ilens   = (const int*)d_in[4];

    float* ws = (float*)d_ws;
    float* W = ws;                                        // BF*T floats
    float2* Rws = (float2*)(ws + (size_t)BF * T);         // BF*K*K float2
    float2* Gws = Rws + (size_t)BF * K * K;               // BF*K*C float2 (P then G in-place)

    power_kernel<<<BF, 256, 0, stream>>>(sep_r, sep_i, W);
    rp_mfma_kernel<<<BF, 64, 0, stream>>>(mix_r, mix_i, W, Rws, Gws);
    solve_kernel<<<BF, 64, 0, stream>>>(Rws, Gws, Gws);
    x_mfma_kernel<<<BF * 4, 64, 0, stream>>>(mix_r, mix_i, Gws, ilens, (float2*)d_out);
}

// Round 17
// 191.018 us; speedup vs baseline: 1.2508x; 1.1051x over previous
//
#include <hip/hip_runtime.h>

#define B 8
#define F 257
#define C 8
#define T 800
#define TAPS 5
#define DELAY 3
#define K 40         // TAPS*C
#define NCOL 48      // K + C
#define T0 7         // DELAY + TAPS - 1
#define BF (B*F)     // 2056

typedef __bf16 bf16x8 __attribute__((ext_vector_type(8)));
typedef __bf16 bf16x4 __attribute__((ext_vector_type(4)));
typedef float f32x4 __attribute__((ext_vector_type(4)));

struct PF { float4 v[3]; };

// ---------------- kernel 1: sqrt inverse power weights (0 for t<T0) ----------------
__global__ __launch_bounds__(256) void power_kernel(const float* __restrict__ sr,
                                                    const float* __restrict__ si,
                                                    float* __restrict__ W) {
    int bf = blockIdx.x;
    const float* srp = sr + (size_t)bf * C * T;
    const float* sip = si + (size_t)bf * C * T;
    int t0 = threadIdx.x * 4;
    if (t0 < T) {
        float s[4] = {0.f, 0.f, 0.f, 0.f};
#pragma unroll
        for (int c = 0; c < C; ++c) {
            float4 a = *(const float4*)(srp + c * T + t0);
            float4 b = *(const float4*)(sip + c * T + t0);
            s[0] = fmaf(a.x, a.x, fmaf(b.x, b.x, s[0]));
            s[1] = fmaf(a.y, a.y, fmaf(b.y, b.y, s[1]));
            s[2] = fmaf(a.z, a.z, fmaf(b.z, b.z, s[2]));
            s[3] = fmaf(a.w, a.w, fmaf(b.w, b.w, s[3]));
        }
        float4 w;
        float* wp = (float*)&w;
#pragma unroll
        for (int e = 0; e < 4; ++e) {
            float v = fmaxf(s[e] * (1.0f / C), 1e-7f);
            wp[e] = (t0 + e < T0) ? 0.f : rsqrtf(v);   // sqrt(1/power)
        }
        *(float4*)(W + (size_t)bf * T + t0) = w;
    }
}

// ---------------- kernel 2: R,P via bf16 MFMA — 4 waves/block (reverted, best measured) ----------------
#define WB 10624

__global__ __launch_bounds__(256, 3) void rp_mfma_kernel(const float* __restrict__ mr,
                                                         const float* __restrict__ mi,
                                                         const float* __restrict__ W,
                                                         float2* __restrict__ Rout,
                                                         float2* __restrict__ Pout) {
    __shared__ __align__(16) unsigned char SH[4 * WB];
    const int lane = threadIdx.x & 63;
    const int wid = threadIdx.x >> 6;
    const int bf = blockIdx.x * 4 + wid;
    unsigned char* base = SH + wid * WB;
    float* sre = (float*)(base + 7680);
    float* sim_ = (float*)(base + 9088);
    float* wsh = (float*)(base + 10496);

    const float* mrp = mr + (size_t)bf * C * T;
    const float* mip = mi + (size_t)bf * C * T;
    const float* Wp  = W  + (size_t)bf * T;

    const int q = lane >> 4, col = lane & 15;
    const int pc = lane >> 3, pg = lane & 7;     // phase-B task: channel, 4t-group

    const int PM[6] = {0, 0, 0, 1, 1, 2};
    const int PN[6] = {0, 1, 2, 1, 2, 2};

    f32x4 accRe[6], accIr[6], accRi[6];
#pragma unroll
    for (int p = 0; p < 6; ++p) {
        accRe[p] = (f32x4){0.f, 0.f, 0.f, 0.f};
        accIr[p] = (f32x4){0.f, 0.f, 0.f, 0.f};
        accRi[p] = (f32x4){0.f, 0.f, 0.f, 0.f};
    }

    for (int ks = 0; ks < 25; ++ks) {
        const int tb = ks * 32;

        // ---- Phase A: vectorized global -> fp32 LDS scratch ----
#pragma unroll
        for (int it = 0; it < 3; ++it) {
            int task = lane + it * 64;
            if (task < 160) {
                int pl = task / 80;
                int rem = task - pl * 80;
                int c = rem / 10, grp = rem - c * 10;
                int tg = tb - 8 + grp * 4;
                const float* srcp = pl ? mip : mrp;
                float4 v = make_float4(0.f, 0.f, 0.f, 0.f);
                if (tg >= 0) v = *(const float4*)(srcp + c * T + tg);
                *(float4*)((pl ? sim_ : sre) + c * 44 + grp * 4) = v;
            } else if (task < 168) {
                int grp = task - 160;
                *(float4*)(wsh + grp * 4) = *(const float4*)(Wp + tb + grp * 4);
            }
        }

        // ---- Phase B: build 6 shift-variant bf16 rows from scratch ----
        {
            float yre[12], yim[12];
            int ybase = pc * 44 + pg * 4;
#pragma unroll
            for (int i = 1; i <= 11; ++i) {
                yre[i] = sre[ybase + i];
                yim[i] = sim_[ybase + i];
            }
            float4 w4 = *(const float4*)(wsh + pg * 4);
            float wv[4] = {w4.x, w4.y, w4.z, w4.w};
#pragma unroll
            for (int v = 0; v < 6; ++v) {
                int row = (v < 5) ? (v * 8 + pc) : (40 + pc);
                int off = (v < 5) ? (5 - v) : 8;
                bf16x4 zr, zi;
#pragma unroll
                for (int e = 0; e < 4; ++e) {
                    zr[e] = (__bf16)(wv[e] * yre[off + e]);
                    zi[e] = (__bf16)(wv[e] * yim[off + e]);
                }
                *(bf16x4*)(base + row * 80 + pg * 8) = zr;
                *(bf16x4*)(base + 3840 + row * 80 + pg * 8) = zi;
            }
        }

        // ---- fragments (shared A/B operand) + 24 MFMA ----
        bf16x8 fr[3], fi[3];
#pragma unroll
        for (int X = 0; X < 3; ++X) {
            fr[X] = *(const bf16x8*)(base + (X * 16 + col) * 80 + q * 16);
            fi[X] = *(const bf16x8*)(base + 3840 + (X * 16 + col) * 80 + q * 16);
        }
#pragma unroll
        for (int p = 0; p < 6; ++p) {
            int mt = PM[p], nt = PN[p];
            accRe[p] = __builtin_amdgcn_mfma_f32_16x16x32_bf16(fr[mt], fr[nt], accRe[p], 0, 0, 0);
            accRe[p] = __builtin_amdgcn_mfma_f32_16x16x32_bf16(fi[mt], fi[nt], accRe[p], 0, 0, 0);
            accIr[p] = __builtin_amdgcn_mfma_f32_16x16x32_bf16(fi[mt], fr[nt], accIr[p], 0, 0, 0);
            accRi[p] = __builtin_amdgcn_mfma_f32_16x16x32_bf16(fr[mt], fi[nt], accRi[p], 0, 0, 0);
        }
    }

    // ---- epilogue: D row=(lane>>4)*4+reg, col=lane&15 (m89); Hermitian mirror ----
    // EPS_REG added on the diagonal here.
    float2* Rp = Rout + (size_t)bf * K * K;
    float2* Pp = Pout + (size_t)bf * K * C;
#pragma unroll
    for (int p = 0; p < 6; ++p) {
        int mt = PM[p], nt = PN[p];
#pragma unroll
        for (int r = 0; r < 4; ++r) {
            int m = mt * 16 + q * 4 + r;
            int n = nt * 16 + col;
            float re = accRe[p][r];
            float im = accIr[p][r] - accRi[p][r];
            if (m < K) {
                if (n < K) {
                    if (m == n) re += 1e-10f;
                    Rp[m * K + n] = make_float2(re, im);
                } else {
                    Pp[m * C + (n - K)] = make_float2(re, im);
                }
            }
            if (mt != nt && m < K && n < K)
                Rp[n * K + m] = make_float2(re, -im);
        }
    }
}

// ---------------- kernel 3: solve R G = P — register-row Gauss-Jordan, ZERO LDS ----------------
__device__ __forceinline__ float rdlane(float v, int j) {
    return __uint_as_float(__builtin_amdgcn_readlane(__float_as_uint(v), (unsigned)j));
}

__global__ __launch_bounds__(64) void solve_kernel(const float2* __restrict__ Rin,
                                                   const float2* __restrict__ Pin,
                                                   float2* __restrict__ Gout) {
    const int bf = blockIdx.x;
    const int lane = threadIdx.x;
    const bool act = lane < K;

    float2 row[NCOL];
    {
        const float4* Rp4 = (const float4*)(Rin + (size_t)bf * K * K + (size_t)(act ? lane : 0) * K);
        const float4* Pp4 = (const float4*)(Pin + (size_t)bf * K * C + (size_t)(act ? lane : 0) * C);
#pragma unroll
        for (int m = 0; m < K / 2; ++m) {
            float4 v = Rp4[m];
            if (!act) v = make_float4(0.f, 0.f, 0.f, 0.f);
            row[2 * m]     = make_float2(v.x, v.y);
            row[2 * m + 1] = make_float2(v.z, v.w);
        }
#pragma unroll
        for (int m = 0; m < C / 2; ++m) {
            float4 v = Pp4[m];
            if (!act) v = make_float4(0.f, 0.f, 0.f, 0.f);
            row[K + 2 * m]     = make_float2(v.x, v.y);
            row[K + 2 * m + 1] = make_float2(v.z, v.w);
        }
    }

#pragma unroll
    for (int j = 0; j < K; ++j) {
        float dx = rdlane(row[j].x, j);
        float dy = rdlane(row[j].y, j);
        float den = fmaf(dx, dx, dy * dy);
        float r = 1.0f / den;
        float ix = dx * r;
        float iy = -dy * r;
        float lx = row[j].x * ix - row[j].y * iy;
        float ly = row[j].x * iy + row[j].y * ix;
        bool isj = (lane == j);
        lx = isj ? (1.0f - ix) : lx;
        ly = isj ? (0.0f - iy) : ly;
#pragma unroll
        for (int n = j; n < NCOL; ++n) {
            float ux = rdlane(row[n].x, j);
            float uy = rdlane(row[n].y, j);
            row[n].x = fmaf(-lx, ux, fmaf( ly, uy, row[n].x));
            row[n].y = fmaf(-lx, uy, fmaf(-ly, ux, row[n].y));
        }
    }

    if (act) {
        float4* Gp = (float4*)(Gout + (size_t)bf * K * C + (size_t)lane * C);
#pragma unroll
        for (int m = 0; m < C / 2; ++m)
            Gp[m] = make_float4(row[K + 2 * m].x, row[K + 2 * m].y,
                                row[K + 2 * m + 1].x, row[K + 2 * m + 1].y);
    }
}

// ---------------- kernel 4: X via bf16 MFMA — prefetch + epilogue-Y-from-LDS ----------------
#define XSTR 144
#define XWB 12032

__device__ __forceinline__ PF x_load(const float* __restrict__ mrp,
                                     const float* __restrict__ mip,
                                     int tb, int lane) {
    PF p;
#pragma unroll
    for (int it = 0; it < 3; ++it) {
        int task = lane + it * 64;
        float4 v = make_float4(0.f, 0.f, 0.f, 0.f);
        if (task < 160) {
            int pl = task / 80;
            int rem = task - pl * 80;
            int c = rem / 10, grp = rem - c * 10;
            int tg = tb - 8 + grp * 4;
            const float* srcp = pl ? mip : mrp;
            if (tg >= 0) v = *(const float4*)(srcp + c * T + tg);
        }
        p.v[it] = v;
    }
    return p;
}

__device__ __forceinline__ void x_store(const PF& p, float* sre, float* sim_, int lane) {
#pragma unroll
    for (int it = 0; it < 3; ++it) {
        int task = lane + it * 64;
        if (task < 160) {
            int pl = task / 80;
            int rem = task - pl * 80;
            int c = rem / 10, grp = rem - c * 10;
            *(float4*)((pl ? sim_ : sre) + c * 44 + grp * 4) = p.v[it];
        }
    }
}

__global__ __launch_bounds__(64) void x_mfma_kernel(const float* __restrict__ mr,
                                                    const float* __restrict__ mi,
                                                    const float2* __restrict__ Gin,
                                                    const int* __restrict__ ilens,
                                                    float2* __restrict__ out) {
    __shared__ __align__(16) unsigned char SH[XWB];
    const int lane = threadIdx.x;
    const int gid = blockIdx.x;
    const int bf = gid >> 2;
    const int split = gid & 3;
    const int ck0 = (split == 0) ? 0 : (1 + split * 6);
    const int nck = (split == 0) ? 7 : 6;
    unsigned char* base = SH;
    float* sre = (float*)(base + 9216);
    float* sim_ = (float*)(base + 10624);

    const float* mrp = mr + (size_t)bf * C * T;
    const float* mip = mi + (size_t)bf * C * T;
    const float2* Gp = Gin + (size_t)bf * K * C;
    float2* outp = out + (size_t)bf * C * T;
    const int len = ilens[bf / F];

    const int q = lane >> 4, col = lane & 15;
    const int t2 = lane >> 1, half = lane & 1;

    // ---- one-time: zero-fill bytes [80,128) of all rows (a = 40..63 -> 0.0) ----
#pragma unroll
    for (int pl = 0; pl < 2; ++pl) {
        unsigned char* pb = base + pl * 4608 + t2 * XSTR + 80 + half * 24;
        *(float2*)(pb)      = make_float2(0.f, 0.f);
        *(float2*)(pb + 8)  = make_float2(0.f, 0.f);
        *(float2*)(pb + 16) = make_float2(0.f, 0.f);
    }

    // ---- A fragments: G (and -Gi) in registers, built once ----
    bf16x8 Agr[2], Agi[2], Agin[2];
#pragma unroll
    for (int ks = 0; ks < 2; ++ks)
#pragma unroll
        for (int j = 0; j < 8; ++j) {
            int a = ks * 32 + q * 8 + j;
            float2 g = make_float2(0.f, 0.f);
            if (a < K && col < C) g = Gp[a * C + col];
            Agr[ks][j]  = (__bf16)g.x;
            Agi[ks][j]  = (__bf16)g.y;
            Agin[ks][j] = (__bf16)(-g.y);
        }

    PF cur = x_load(mrp, mip, ck0 * 32, lane);

    for (int ci = 0; ci < nck; ++ci) {
        const int tb = (ck0 + ci) * 32;

        // ---- write staged chunk; prefetch next ----
        x_store(cur, sre, sim_, lane);
        if (ci + 1 < nck) cur = x_load(mrp, mip, tb + 32, lane);

        // ---- Phase B: build transposed bf16 Ytilde rows [t_local][a] ----
#pragma unroll
        for (int i = 0; i < 5; ++i) {
            int abase = half * 20 + 4 * i;
            bf16x4 zr, zi;
#pragma unroll
            for (int e2 = 0; e2 < 4; ++e2) {
                int a = abase + e2;
                int v = a >> 3, c = a & 7;
                int idx = c * 44 + t2 + 5 - v;   // Y[c][tb+t2-3-v]
                zr[e2] = (__bf16)sre[idx];
                zi[e2] = (__bf16)sim_[idx];
            }
            *(bf16x4*)(base + t2 * XSTR + abase * 2) = zr;
            *(bf16x4*)(base + 4608 + t2 * XSTR + abase * 2) = zi;
        }

        // ---- two 16-t tiles: 8 MFMA each + epilogue (Y from scratch LDS) ----
#pragma unroll
        for (int tt = 0; tt < 2; ++tt) {
            const int trow = tt * 16 + col;
            f32x4 accRe = (f32x4){0.f, 0.f, 0.f, 0.f};
            f32x4 accIm = (f32x4){0.f, 0.f, 0.f, 0.f};
#pragma unroll
            for (int ks = 0; ks < 2; ++ks) {
                bf16x8 byr = *(const bf16x8*)(base + trow * XSTR + ks * 64 + q * 16);
                bf16x8 byi = *(const bf16x8*)(base + 4608 + trow * XSTR + ks * 64 + q * 16);
                accRe = __builtin_amdgcn_mfma_f32_16x16x32_bf16(Agr[ks], byr, accRe, 0, 0, 0);
                accRe = __builtin_amdgcn_mfma_f32_16x16x32_bf16(Agi[ks], byi, accRe, 0, 0, 0);
                accIm = __builtin_amdgcn_mfma_f32_16x16x32_bf16(Agr[ks], byi, accIm, 0, 0, 0);
                accIm = __builtin_amdgcn_mfma_f32_16x16x32_bf16(Agin[ks], byr, accIm, 0, 0, 0);
            }
            // D row=(lane>>4)*4+r (=e), col=lane&15 (=t offset) [m89]
            if (q < 2) {
                int t = tb + tt * 16 + col;
                int l = tt * 16 + col + 8;       // scratch index of t
                bool ok = (t < len);
#pragma unroll
                for (int r = 0; r < 4; ++r) {
                    int e = q * 4 + r;
                    float yr = sre[e * 44 + l];
                    float yi = sim_[e * 44 + l];
                    float2 v = ok ? make_float2(yr - accRe[r], yi - accIm[r])
                                  : make_float2(0.f, 0.f);
                    outp[e * T + t] = v;
                }
            }
        }
    }
}

extern "C" void kernel_launch(void* const* d_in, const int* in_sizes, int n_in,
                              void* d_out, int out_size, void* d_ws, size_t ws_size,
                              hipStream_t stream) {
    const float* sep_r = (const float*)d_in[0];
    const float* sep_i = (const float*)d_in[1];
    const float* mix_r = (const float*)d_in[2];
    const float* mix_i = (const float*)d_in[3];
    const int* ilens   = (const int*)d_in[4];

    float* ws = (float*)d_ws;
    float* W = ws;                                        // BF*T floats
    float2* Rws = (float2*)(ws + (size_t)BF * T);         // BF*K*K float2
    float2* Gws = Rws + (size_t)BF * K * K;               // BF*K*C float2 (P then G in-place)

    power_kernel<<<BF, 256, 0, stream>>>(sep_r, sep_i, W);
    rp_mfma_kernel<<<BF / 4, 256, 0, stream>>>(mix_r, mix_i, W, Rws, Gws);
    solve_kernel<<<BF, 64, 0, stream>>>(Rws, Gws, Gws);
    x_mfma_kernel<<<BF * 4, 64, 0, stream>>>(mix_r, mix_i, Gws, ilens, (float2*)d_out);
}